// Round 5
// baseline (4411.315 us; speedup 1.0000x reference)
//
#include <hip/hip_runtime.h>
#include <hip/hip_bf16.h>
#include <math.h>

// Problem constants (from reference)
#define B_   4
#define L_   1024
#define D_   1024
#define H_   16
#define NL_  4
#define DH_  64
#define DFF_ 4096
#define EPS_ 1e-5f

typedef unsigned short u16;
typedef __attribute__((ext_vector_type(8))) short short8;
typedef __attribute__((ext_vector_type(4))) float f32x4;

static __device__ __forceinline__ u16 f2bf(float x) {
  union { float f; unsigned u; } c;
  c.f = x;
  unsigned r = c.u + 0x7fffu + ((c.u >> 16) & 1u);  // RNE
  return (u16)(r >> 16);
}
static __device__ __forceinline__ float bf2f(u16 x) {
  union { unsigned u; float f; } c;
  c.u = ((unsigned)x) << 16;
  return c.f;
}

// ---------------------------------------------------------------------------
// Transpose + cast: W fp32 [R,C] -> Wt bf16 [C,R]. grid (C/64, R/64), 256 thr.
// ---------------------------------------------------------------------------
__global__ __launch_bounds__(256) void transpose_cast_kernel(
    const float* __restrict__ W, u16* __restrict__ Wt, int R, int C) {
  __shared__ float tile[64][65];
  int r0 = blockIdx.y * 64, c0 = blockIdx.x * 64;
  int t = threadIdx.x;
#pragma unroll
  for (int i = 0; i < 4; i++) {
    int f = t + i * 256;
    int rr = f >> 4, c4 = f & 15;
    float4 v = *(const float4*)(W + (size_t)(r0 + rr) * C + c0 + c4 * 4);
    tile[rr][c4 * 4 + 0] = v.x;
    tile[rr][c4 * 4 + 1] = v.y;
    tile[rr][c4 * 4 + 2] = v.z;
    tile[rr][c4 * 4 + 3] = v.w;
  }
  __syncthreads();
#pragma unroll
  for (int i = 0; i < 4; i++) {
    int f = t + i * 256;
    int cc = f >> 4, rq = f & 15;
    unsigned p0 = (unsigned)f2bf(tile[rq * 4 + 0][cc]) |
                  ((unsigned)f2bf(tile[rq * 4 + 1][cc]) << 16);
    unsigned p1 = (unsigned)f2bf(tile[rq * 4 + 2][cc]) |
                  ((unsigned)f2bf(tile[rq * 4 + 3][cc]) << 16);
    uint2 q; q.x = p0; q.y = p1;
    *(uint2*)(Wt + (size_t)(c0 + cc) * R + r0 + rq * 4) = q;
  }
}

// ---------------------------------------------------------------------------
// RMSNorm over D=1024, fp32 out (final norm only).
// ---------------------------------------------------------------------------
__global__ __launch_bounds__(256) void rmsnorm_kernel(
    const float* __restrict__ in, const float* __restrict__ w,
    float* __restrict__ out) {
  int row = blockIdx.x;
  const float4* x4 = (const float4*)(in + (size_t)row * D_);
  float4* y4 = (float4*)(out + (size_t)row * D_);
  const float4* w4 = (const float4*)w;
  int t = threadIdx.x;
  float4 v = x4[t];
  float ss = v.x * v.x + v.y * v.y + v.z * v.z + v.w * v.w;
#pragma unroll
  for (int off = 32; off > 0; off >>= 1) ss += __shfl_down(ss, off, 64);
  __shared__ float red[4];
  if ((t & 63) == 0) red[t >> 6] = ss;
  __syncthreads();
  float tot = red[0] + red[1] + red[2] + red[3];
  float r = rsqrtf(tot * (1.0f / D_) + EPS_);
  float4 wv = w4[t];
  float4 o;
  o.x = v.x * r * wv.x;
  o.y = v.y * r * wv.y;
  o.z = v.z * r * wv.z;
  o.w = v.w * r * wv.w;
  y4[t] = o;
}

// ---------------------------------------------------------------------------
// RMSNorm, bf16 out (layer norms feeding bf16 GEMMs).
// ---------------------------------------------------------------------------
__global__ __launch_bounds__(256) void rmsnorm_bf16_kernel(
    const float* __restrict__ in, const float* __restrict__ w,
    u16* __restrict__ out) {
  int row = blockIdx.x;
  const float4* x4 = (const float4*)(in + (size_t)row * D_);
  const float4* w4 = (const float4*)w;
  int t = threadIdx.x;
  float4 v = x4[t];
  float ss = v.x * v.x + v.y * v.y + v.z * v.z + v.w * v.w;
#pragma unroll
  for (int off = 32; off > 0; off >>= 1) ss += __shfl_down(ss, off, 64);
  __shared__ float red[4];
  if ((t & 63) == 0) red[t >> 6] = ss;
  __syncthreads();
  float tot = red[0] + red[1] + red[2] + red[3];
  float r = rsqrtf(tot * (1.0f / D_) + EPS_);
  float4 wv = w4[t];
  unsigned p0 = (unsigned)f2bf(v.x * r * wv.x) |
                ((unsigned)f2bf(v.y * r * wv.y) << 16);
  unsigned p1 = (unsigned)f2bf(v.z * r * wv.z) |
                ((unsigned)f2bf(v.w * r * wv.w) << 16);
  uint2 q; q.x = p0; q.y = p1;
  *(uint2*)(out + (size_t)row * D_ + t * 4) = q;
}

// ---------------------------------------------------------------------------
// Per-head RMSNorm(Dh=64) + RoPE, in place on bf16 qkv [M, 3D].
// ---------------------------------------------------------------------------
__global__ __launch_bounds__(256) void qknorm_rope_kernel(
    u16* __restrict__ qkv, const int* __restrict__ positions,
    const float* __restrict__ qn, const float* __restrict__ kn) {
  int tok = blockIdx.x;  // b*L + l
  int p = blockIdx.y * 4 + (threadIdx.x >> 6);
  int d = threadIdx.x & 63;
  int isK = p >> 4;
  int h = p & 15;
  const float* w = isK ? kn : qn;
  u16* ptr = qkv + (size_t)tok * (3 * D_) + (size_t)isK * D_ + h * 64;
  float v = bf2f(ptr[d]);
  float ss = v * v;
#pragma unroll
  for (int off = 1; off < 64; off <<= 1) ss += __shfl_xor(ss, off, 64);
  float r = rsqrtf(ss * (1.0f / 64.0f) + EPS_);
  v = v * r * w[d];
  float pv = __shfl_xor(v, 1, 64);
  float outv = v;
  if (d < 32) {
    int i = d >> 1;
    float freq = __expf(-logf(10000.0f) * (float)(2 * i) * (1.0f / 32.0f));
    float th = (float)positions[tok] * freq;
    float s, c;
    __sincosf(th, &s, &c);
    outv = (d & 1) ? (pv * s + v * c) : (v * c - pv * s);
  }
  ptr[d] = f2bf(outv);
}

// ---------------------------------------------------------------------------
// Pipelined bf16 MFMA GEMM. A [M,K] bf16, Bt [N,K] bf16 (B^T). Tile =
// (AI*32) x 128, BK=32. Register-staged: global->VGPR loads for iter k+1 are
// issued before the compute barrier of iter k (VGPR loads don't force the
// vmcnt(0) drain at s_barrier that global_load_lds does), ds_write at top.
// 4 waves 2x2. AI=4: 128-row tile (2 A-subtiles staged/thread). AI=2: 64-row
// tile (1/thread) -> 2x the blocks for N=1024 GEMMs.
// MODE 1: C f32 += acc.  MODE 2: C bf16 = acc.
// ---------------------------------------------------------------------------
template <int MODE, int AI>
__global__ __launch_bounds__(256) void gemm_mfma(
    const u16* __restrict__ A, const u16* __restrict__ Bt,
    void* __restrict__ C, int M, int N, int K) {
  const int NA = AI / 2;  // A-subtile loads per thread
  __shared__ u16 As[AI * 1024];  // (AI*32) x 32
  __shared__ u16 Bs[4096];       // 128 x 32
  int t = threadIdx.x;
  int lane = t & 63, wv = t >> 6;
  int wm = wv >> 1, wn = wv & 1;
  int m0 = blockIdx.y * (AI * 32), n0 = blockIdx.x * 128;
  int lm = lane & 15, lk = lane >> 4;

  const u16* pa[NA];
  const u16* pb[2];
#pragma unroll
  for (int i = 0; i < NA; i++)
    pa[i] = A + (size_t)(m0 + (wv * NA + i) * 16 + lm) * K + lk * 8;
#pragma unroll
  for (int i = 0; i < 2; i++)
    pb[i] = Bt + (size_t)(n0 + (wv * 2 + i) * 16 + lm) * K + lk * 8;

  uint4 ca[NA], cb[2];
#pragma unroll
  for (int i = 0; i < NA; i++) ca[i] = *(const uint4*)pa[i];
#pragma unroll
  for (int i = 0; i < 2; i++) cb[i] = *(const uint4*)pb[i];

  f32x4 acc[AI][4];
#pragma unroll
  for (int i = 0; i < AI; i++)
#pragma unroll
    for (int j = 0; j < 4; j++) acc[i][j] = (f32x4)0.0f;

  for (int k0 = 0; k0 < K; k0 += 32) {
#pragma unroll
    for (int i = 0; i < NA; i++)
      *(uint4*)(As + (wv * NA + i) * 512 + lane * 8) = ca[i];
#pragma unroll
    for (int i = 0; i < 2; i++)
      *(uint4*)(Bs + (wv * 2 + i) * 512 + lane * 8) = cb[i];
    int kn = (k0 + 32 < K) ? (k0 + 32) : 0;
    uint4 na[NA], nb[2];
#pragma unroll
    for (int i = 0; i < NA; i++) na[i] = *(const uint4*)(pa[i] + kn);
#pragma unroll
    for (int i = 0; i < 2; i++) nb[i] = *(const uint4*)(pb[i] + kn);
    __syncthreads();
    short8 a[AI], b[4];
#pragma unroll
    for (int i = 0; i < AI; i++)
      a[i] = *(const short8*)(As + (wm * AI + i) * 512 + lane * 8);
#pragma unroll
    for (int j = 0; j < 4; j++)
      b[j] = *(const short8*)(Bs + (wn * 4 + j) * 512 + lane * 8);
#pragma unroll
    for (int i = 0; i < AI; i++)
#pragma unroll
      for (int j = 0; j < 4; j++)
        acc[i][j] = __builtin_amdgcn_mfma_f32_16x16x32_bf16(
            a[i], b[j], acc[i][j], 0, 0, 0);
    __syncthreads();
#pragma unroll
    for (int i = 0; i < NA; i++) ca[i] = na[i];
#pragma unroll
    for (int i = 0; i < 2; i++) cb[i] = nb[i];
  }

  int rb = (lane >> 4) * 4;
  int cl = lane & 15;
  size_t colbase = (size_t)(n0 + wn * 64 + cl);
#pragma unroll
  for (int i = 0; i < AI; i++) {
#pragma unroll
    for (int r = 0; r < 4; r++) {
      size_t row = (size_t)(m0 + wm * (AI * 16) + i * 16 + rb + r);
      if (MODE == 1) {
        float* p = (float*)C + row * N + colbase;
#pragma unroll
        for (int j = 0; j < 4; j++) p[j * 16] += acc[i][j][r];
      } else {
        u16* p = (u16*)C + row * N + colbase;
#pragma unroll
        for (int j = 0; j < 4; j++) p[j * 16] = f2bf(acc[i][j][r]);
      }
    }
  }
}

// ---------------------------------------------------------------------------
// Fused gate+up FFN GEMM: ff[M,DFF] = silu(A@Wg) * (A@Wu), A [M,1024] bf16,
// WgT/WuT [4096,1024] bf16 (transposed). 128x128 tile, BK=32, same pipelined
// register staging; 32 MFMA per wave per K-iter (gate + up accumulators).
// ---------------------------------------------------------------------------
__global__ __launch_bounds__(256) void gemm_dff_fused(
    const u16* __restrict__ A, const u16* __restrict__ WgT,
    const u16* __restrict__ WuT, u16* __restrict__ ff, int M) {
  const int K = D_;
  __shared__ u16 As[4096];
  __shared__ u16 Gs[4096];
  __shared__ u16 Us[4096];
  int t = threadIdx.x;
  int lane = t & 63, wv = t >> 6;
  int wm = wv >> 1, wn = wv & 1;
  int m0 = blockIdx.y * 128, n0 = blockIdx.x * 128;
  int lm = lane & 15, lk = lane >> 4;

  const u16* pa[2];
  const u16* pg[2];
  const u16* pu[2];
#pragma unroll
  for (int i = 0; i < 2; i++) {
    int s = wv * 2 + i;
    pa[i] = A + (size_t)(m0 + s * 16 + lm) * K + lk * 8;
    pg[i] = WgT + (size_t)(n0 + s * 16 + lm) * K + lk * 8;
    pu[i] = WuT + (size_t)(n0 + s * 16 + lm) * K + lk * 8;
  }
  uint4 ca[2], cg[2], cu[2];
#pragma unroll
  for (int i = 0; i < 2; i++) {
    ca[i] = *(const uint4*)pa[i];
    cg[i] = *(const uint4*)pg[i];
    cu[i] = *(const uint4*)pu[i];
  }

  f32x4 accg[4][4], accu[4][4];
#pragma unroll
  for (int i = 0; i < 4; i++)
#pragma unroll
    for (int j = 0; j < 4; j++) {
      accg[i][j] = (f32x4)0.0f;
      accu[i][j] = (f32x4)0.0f;
    }

  for (int k0 = 0; k0 < K; k0 += 32) {
#pragma unroll
    for (int i = 0; i < 2; i++) {
      int s = wv * 2 + i;
      *(uint4*)(As + s * 512 + lane * 8) = ca[i];
      *(uint4*)(Gs + s * 512 + lane * 8) = cg[i];
      *(uint4*)(Us + s * 512 + lane * 8) = cu[i];
    }
    int kn = (k0 + 32 < K) ? (k0 + 32) : 0;
    uint4 na[2], ng[2], nu[2];
#pragma unroll
    for (int i = 0; i < 2; i++) {
      na[i] = *(const uint4*)(pa[i] + kn);
      ng[i] = *(const uint4*)(pg[i] + kn);
      nu[i] = *(const uint4*)(pu[i] + kn);
    }
    __syncthreads();
    short8 a[4], g[4], u[4];
#pragma unroll
    for (int i = 0; i < 4; i++) {
      a[i] = *(const short8*)(As + (wm * 4 + i) * 512 + lane * 8);
      g[i] = *(const short8*)(Gs + (wn * 4 + i) * 512 + lane * 8);
      u[i] = *(const short8*)(Us + (wn * 4 + i) * 512 + lane * 8);
    }
#pragma unroll
    for (int i = 0; i < 4; i++)
#pragma unroll
      for (int j = 0; j < 4; j++) {
        accg[i][j] = __builtin_amdgcn_mfma_f32_16x16x32_bf16(
            a[i], g[j], accg[i][j], 0, 0, 0);
        accu[i][j] = __builtin_amdgcn_mfma_f32_16x16x32_bf16(
            a[i], u[j], accu[i][j], 0, 0, 0);
      }
    __syncthreads();
#pragma unroll
    for (int i = 0; i < 2; i++) {
      ca[i] = na[i];
      cg[i] = ng[i];
      cu[i] = nu[i];
    }
  }

  int rb = (lane >> 4) * 4;
  int cl = lane & 15;
#pragma unroll
  for (int i = 0; i < 4; i++) {
#pragma unroll
    for (int r = 0; r < 4; r++) {
      size_t row = (size_t)(m0 + wm * 64 + i * 16 + rb + r);
      u16* p = ff + row * DFF_ + n0 + wn * 64 + cl;
#pragma unroll
      for (int j = 0; j < 4; j++) {
        float gg = accg[i][j][r];
        float uu = accu[i][j][r];
        p[j * 16] = f2bf((gg / (1.0f + __expf(-gg))) * uu);
      }
    }
  }
}

// ---------------------------------------------------------------------------
// MFMA flash attention (unchanged from round 4).
// ---------------------------------------------------------------------------
__global__ __launch_bounds__(256) void attn_mfma_kernel(
    const u16* __restrict__ qkv, const int* __restrict__ var_id,
    const float* __restrict__ bias_l, u16* __restrict__ o) {
  __shared__ u16 Ps[4][16 * 72];  // per-wave P [query][key]
  __shared__ u16 Vt[64 * 72];     // V^T [dim][key]
  __shared__ int vks[64];
  int b = blockIdx.z, h = blockIdx.y, q0 = blockIdx.x * 64;
  int t = threadIdx.x, lane = t & 63, w = t >> 6;
  int cl = lane & 15, qd = lane >> 4;
  const size_t ROW = 3 * D_;
  const u16* qbase = qkv + (size_t)(b * L_) * ROW + h * 64;
  const u16* kbase = qbase + D_;
  const u16* vbase = qbase + 2 * D_;
  const float scale = 0.125f;  // 1/sqrt(64)

  int qrow = q0 + w * 16 + cl;
  short8 aq0 = *(const short8*)(qbase + (size_t)qrow * ROW + qd * 8);
  short8 aq1 = *(const short8*)(qbase + (size_t)qrow * ROW + 32 + qd * 8);

  int vq[4];
#pragma unroll
  for (int r = 0; r < 4; r++)
    vq[r] = var_id[b * L_ + q0 + w * 16 + qd * 4 + r];
  float b0 = bias_l[h], b1 = bias_l[H_ + h];

  float m_i[4], l_i[4];
  f32x4 oc[4];
#pragma unroll
  for (int r = 0; r < 4; r++) { m_i[r] = -1e30f; l_i[r] = 0.0f; }
#pragma unroll
  for (int ds = 0; ds < 4; ds++) oc[ds] = (f32x4)0.0f;

  int kp = t & 31, g = t >> 5;

  for (int kt = 0; kt < 16; kt++) {
    int k0 = kt * 64;
    {
      const u16* v0 = vbase + (size_t)(k0 + 2 * kp) * ROW + g * 8;
      short8 va = *(const short8*)v0;
      short8 vb = *(const short8*)(v0 + ROW);
#pragma unroll
      for (int j = 0; j < 8; j++) {
        unsigned pk = (unsigned)(u16)va[j] | ((unsigned)(u16)vb[j] << 16);
        *(unsigned*)&Vt[(g * 8 + j) * 72 + 2 * kp] = pk;
      }
      if (t < 64) vks[t] = var_id[b * L_ + k0 + t];
    }
    __syncthreads();

    f32x4 s[4];
#pragma unroll
    for (int j = 0; j < 4; j++) {
      const u16* kr = kbase + (size_t)(k0 + j * 16 + cl) * ROW;
      short8 bk0 = *(const short8*)(kr + qd * 8);
      short8 bk1 = *(const short8*)(kr + 32 + qd * 8);
      f32x4 a = (f32x4)0.0f;
      a = __builtin_amdgcn_mfma_f32_16x16x32_bf16(aq0, bk0, a, 0, 0, 0);
      a = __builtin_amdgcn_mfma_f32_16x16x32_bf16(aq1, bk1, a, 0, 0, 0);
      s[j] = a;
    }
#pragma unroll
    for (int j = 0; j < 4; j++) {
      int kv = vks[j * 16 + cl];
#pragma unroll
      for (int r = 0; r < 4; r++)
        s[j][r] = s[j][r] * scale + ((kv == vq[r]) ? b1 : b0);
    }
#pragma unroll
    for (int r = 0; r < 4; r++) {
      float rm = fmaxf(fmaxf(s[0][r], s[1][r]), fmaxf(s[2][r], s[3][r]));
#pragma unroll
      for (int off = 1; off < 16; off <<= 1)
        rm = fmaxf(rm, __shfl_xor(rm, off, 64));
      float mnew = fmaxf(m_i[r], rm);
      float alpha = __expf(m_i[r] - mnew);
      m_i[r] = mnew;
      float rs = 0.0f;
#pragma unroll
      for (int j = 0; j < 4; j++) {
        float p = __expf(s[j][r] - mnew);
        s[j][r] = p;
        rs += p;
      }
#pragma unroll
      for (int off = 1; off < 16; off <<= 1) rs += __shfl_xor(rs, off, 64);
      l_i[r] = l_i[r] * alpha + rs;
#pragma unroll
      for (int ds = 0; ds < 4; ds++) oc[ds][r] *= alpha;
    }
#pragma unroll
    for (int j = 0; j < 4; j++)
#pragma unroll
      for (int r = 0; r < 4; r++)
        Ps[w][(qd * 4 + r) * 72 + j * 16 + cl] = f2bf(s[j][r]);

    short8 ap0 = *(const short8*)(&Ps[w][cl * 72 + qd * 8]);
    short8 ap1 = *(const short8*)(&Ps[w][cl * 72 + 32 + qd * 8]);
#pragma unroll
    for (int ds = 0; ds < 4; ds++) {
      const u16* vr = &Vt[(ds * 16 + cl) * 72];
      short8 bv0 = *(const short8*)(vr + qd * 8);
      short8 bv1 = *(const short8*)(vr + 32 + qd * 8);
      oc[ds] = __builtin_amdgcn_mfma_f32_16x16x32_bf16(ap0, bv0, oc[ds], 0, 0, 0);
      oc[ds] = __builtin_amdgcn_mfma_f32_16x16x32_bf16(ap1, bv1, oc[ds], 0, 0, 0);
    }
    __syncthreads();
  }

#pragma unroll
  for (int r = 0; r < 4; r++) {
    float inv = 1.0f / l_i[r];
    size_t row = (size_t)(b * L_ + q0 + w * 16 + qd * 4 + r);
#pragma unroll
    for (int ds = 0; ds < 4; ds++)
      o[row * D_ + h * 64 + ds * 16 + cl] = f2bf(oc[ds][r] * inv);
  }
}

// ---------------------------------------------------------------------------
extern "C" void kernel_launch(void* const* d_in, const int* in_sizes, int n_in,
                              void* d_out, int out_size, void* d_ws,
                              size_t ws_size, hipStream_t stream) {
  (void)in_sizes; (void)n_in; (void)out_size; (void)ws_size;
  const float* x    = (const float*)d_in[0];
  const int* var_id = (const int*)d_in[1];
  const int* pos    = (const int*)d_in[2];
  const float* Wqkv = (const float*)d_in[3];
  const float* Wo   = (const float*)d_in[4];
  const float* n1   = (const float*)d_in[5];
  const float* n2   = (const float*)d_in[6];
  const float* qn   = (const float*)d_in[7];
  const float* kn   = (const float*)d_in[8];
  const float* be   = (const float*)d_in[9];
  const float* Wg   = (const float*)d_in[10];
  const float* Wu   = (const float*)d_in[11];
  const float* Wd   = (const float*)d_in[12];
  const float* fnw  = (const float*)d_in[13];

  float* h = (float*)d_out;  // residual stream (fp32) lives in d_out
  const size_t MB = 1u << 20;
  char* wsb = (char*)d_ws;
  u16* y   = (u16*)(wsb);            // 8 MB  [M,D] bf16
  u16* qkv = (u16*)(wsb + 8*MB);     // 16 MB [M,3D] bf16
  u16* o   = (u16*)(wsb + 24*MB);    // 8 MB  [M,D] bf16
  u16* ff  = (u16*)(wsb + 32*MB);    // 32 MB [M,DFF] bf16
  u16* wT  = (u16*)(wsb + 64*MB);    // ~34 MB transposed weights
  u16* wqkvT = wT;                        // [3072,1024]
  u16* woT   = wqkvT + (size_t)3072*1024; // [1024,1024]
  u16* wgT   = woT   + (size_t)1024*1024; // [4096,1024]
  u16* wuT   = wgT   + (size_t)4096*1024; // [4096,1024]
  u16* wdT   = wuT   + (size_t)4096*1024; // [1024,4096]

  const size_t SZ = (size_t)B_ * L_ * D_;
  hipMemcpyAsync(h, x, SZ * sizeof(float), hipMemcpyDeviceToDevice, stream);

  const int M = B_ * L_;
  for (int l = 0; l < NL_; l++) {
    transpose_cast_kernel<<<dim3(48, 16), 256, 0, stream>>>(
        Wqkv + (size_t)l * D_ * 3 * D_, wqkvT, D_, 3 * D_);
    transpose_cast_kernel<<<dim3(16, 16), 256, 0, stream>>>(
        Wo + (size_t)l * D_ * D_, woT, D_, D_);
    transpose_cast_kernel<<<dim3(64, 16), 256, 0, stream>>>(
        Wg + (size_t)l * D_ * DFF_, wgT, D_, DFF_);
    transpose_cast_kernel<<<dim3(64, 16), 256, 0, stream>>>(
        Wu + (size_t)l * D_ * DFF_, wuT, D_, DFF_);
    transpose_cast_kernel<<<dim3(16, 64), 256, 0, stream>>>(
        Wd + (size_t)l * DFF_ * D_, wdT, DFF_, D_);

    rmsnorm_bf16_kernel<<<M, 256, 0, stream>>>(h, n1 + (size_t)l * D_, y);
    gemm_mfma<2, 4><<<dim3(3 * D_ / 128, M / 128), 256, 0, stream>>>(
        y, wqkvT, qkv, M, 3 * D_, D_);
    qknorm_rope_kernel<<<dim3(M, 8), 256, 0, stream>>>(
        qkv, pos, qn + (size_t)l * DH_, kn + (size_t)l * DH_);
    attn_mfma_kernel<<<dim3(L_ / 64, H_, B_), 256, 0, stream>>>(
        qkv, var_id, be + (size_t)l * 2 * H_, o);
    gemm_mfma<1, 2><<<dim3(D_ / 128, M / 64), 256, 0, stream>>>(
        o, woT, h, M, D_, D_);
    rmsnorm_bf16_kernel<<<M, 256, 0, stream>>>(h, n2 + (size_t)l * D_, y);
    gemm_dff_fused<<<dim3(DFF_ / 128, M / 128), 256, 0, stream>>>(
        y, wgT, wuT, ff, M);
    gemm_mfma<1, 2><<<dim3(D_ / 128, M / 64), 256, 0, stream>>>(
        ff, wdT, h, M, D_, DFF_);
  }
  rmsnorm_kernel<<<M, 256, 0, stream>>>(h, fnw, h);
}